// Round 1
// baseline (384.856 us; speedup 1.0000x reference)
//
#include <hip/hip_runtime.h>
#include <hip/hip_bf16.h>

#define N_NODES 100000
#define N_EDGES 1600000
#define CH 64

// Stage 2: agg[tgt] += gw * x[src], wave-per-edge, lane = channel.
__global__ __launch_bounds__(256) void scatter_kernel(
    const float* __restrict__ x, const int* __restrict__ ei,
    const float* __restrict__ attr, const float* __restrict__ gp,
    float* __restrict__ agg) {
  const int lane = threadIdx.x & 63;
  const int wave = (blockIdx.x * blockDim.x + threadIdx.x) >> 6;
  const int nwaves = (gridDim.x * blockDim.x) >> 6;
  const float inv = 1.0f / (gp[0] * gp[0] + 1e-8f);

  // Each wave grabs 64 edges at a time: per-lane metadata load (coalesced),
  // then 64 broadcast iterations doing the gather + atomic scatter.
  for (int base = wave * 64; base < N_EDGES; base += nwaves * 64) {
    int e = base + lane;
    int s = 0, t = 0;
    float g = 0.0f;
    if (e < N_EDGES) {
      s = ei[e];            // src row
      t = ei[N_EDGES + e];  // tgt row
      float d = attr[3 * e];
      g = expf(-d * d * inv);
    }
    const int cnt = (N_EDGES - base) < 64 ? (N_EDGES - base) : 64;
    for (int j = 0; j < cnt; ++j) {
      int sj = __shfl(s, j);
      int tj = __shfl(t, j);
      float gj = __shfl(g, j);
      float val = x[sj * CH + lane] * gj;
      atomicAdd(&agg[tj * CH + lane], val);
    }
  }
}

// Stage 3: out[r] = (x[r] + agg[r]) @ W + bias, in place (agg lives in out).
__global__ __launch_bounds__(256) void rowgemm_kernel(
    const float* __restrict__ x, const float* __restrict__ W,
    const float* __restrict__ bias, float* __restrict__ out) {
  __shared__ float Wl[CH * CH];
  __shared__ float bl[CH];
  for (int i = threadIdx.x; i < CH * CH; i += 256) Wl[i] = W[i];
  if (threadIdx.x < CH) bl[threadIdx.x] = bias[threadIdx.x];
  __syncthreads();

  const int r = blockIdx.x * blockDim.x + threadIdx.x;
  if (r >= N_NODES) return;

  const float* xr = x + r * CH;
  float* outr = out + r * CH;

  float acc[CH];
#pragma unroll
  for (int c = 0; c < CH; ++c) acc[c] = bl[c];

#pragma unroll
  for (int k4 = 0; k4 < CH / 4; ++k4) {
    float4 xv = *reinterpret_cast<const float4*>(xr + k4 * 4);
    float4 av = *reinterpret_cast<const float4*>(outr + k4 * 4);
    float sv[4] = {xv.x + av.x, xv.y + av.y, xv.z + av.z, xv.w + av.w};
#pragma unroll
    for (int kk = 0; kk < 4; ++kk) {
      const int k = k4 * 4 + kk;
      const float s = sv[kk];
#pragma unroll
      for (int c4 = 0; c4 < CH / 4; ++c4) {
        float4 w = *reinterpret_cast<const float4*>(&Wl[k * CH + c4 * 4]);
        acc[c4 * 4 + 0] += s * w.x;
        acc[c4 * 4 + 1] += s * w.y;
        acc[c4 * 4 + 2] += s * w.z;
        acc[c4 * 4 + 3] += s * w.w;
      }
    }
  }

#pragma unroll
  for (int c4 = 0; c4 < CH / 4; ++c4) {
    float4 o = {acc[c4 * 4 + 0], acc[c4 * 4 + 1], acc[c4 * 4 + 2],
                acc[c4 * 4 + 3]};
    *reinterpret_cast<float4*>(outr + c4 * 4) = o;
  }
}

extern "C" void kernel_launch(void* const* d_in, const int* in_sizes, int n_in,
                              void* d_out, int out_size, void* d_ws,
                              size_t ws_size, hipStream_t stream) {
  const float* x = (const float*)d_in[0];
  const int* ei = (const int*)d_in[1];      // int64 in ref, but JAX x64 is off -> int32
  const float* attr = (const float*)d_in[2];
  const float* W = (const float*)d_in[3];
  const float* bias = (const float*)d_in[4];
  const float* gp = (const float*)d_in[5];
  float* out = (float*)d_out;

  // Stage 1: zero the accumulator (d_out doubles as agg buffer).
  hipMemsetAsync(out, 0, (size_t)N_NODES * CH * sizeof(float), stream);

  // Stage 2: scatter-accumulate gw * x[src] into out[tgt].
  scatter_kernel<<<2048, 256, 0, stream>>>(x, ei, attr, gp, out);

  // Stage 3: out = (x + out) @ W + bias, row-local in-place.
  rowgemm_kernel<<<(N_NODES + 255) / 256, 256, 0, stream>>>(x, W, bias, out);
}

// Round 3
// 344.911 us; speedup vs baseline: 1.1158x; 1.1158x over previous
//
#include <hip/hip_runtime.h>
#include <hip/hip_bf16.h>
#include <stdint.h>

#define N_NODES 100000
#define N_EDGES 1600000
#define CH 64

#define SCAN_CHUNK 1024
#define NB ((N_NODES + SCAN_CHUNK - 1) / SCAN_CHUNK)  // 98

// ---------------- CSR build ----------------

__global__ __launch_bounds__(256) void hist_kernel(const int* __restrict__ ei,
                                                   int* __restrict__ cnt) {
  const int i = blockIdx.x * blockDim.x + threadIdx.x;
  const int stride = gridDim.x * blockDim.x;
  for (int e = i; e < N_EDGES; e += stride)
    atomicAdd(&cnt[ei[N_EDGES + e]], 1);
}

// Per-1024-chunk sums.
__global__ __launch_bounds__(256) void scanA_kernel(const int* __restrict__ cnt,
                                                    int* __restrict__ bsum) {
  __shared__ int sd[256];
  const int base = blockIdx.x * SCAN_CHUNK;
  int s = 0;
#pragma unroll
  for (int k = 0; k < 4; ++k) {
    int idx = base + threadIdx.x * 4 + k;
    if (idx < N_NODES) s += cnt[idx];
  }
  sd[threadIdx.x] = s;
  __syncthreads();
  for (int off = 128; off > 0; off >>= 1) {
    if (threadIdx.x < off) sd[threadIdx.x] += sd[threadIdx.x + off];
    __syncthreads();
  }
  if (threadIdx.x == 0) bsum[blockIdx.x] = sd[0];
}

// Exclusive scan of the NB (<=128) chunk sums, single block.
__global__ __launch_bounds__(128) void scanB_kernel(int* __restrict__ bsum) {
  __shared__ int sd[128];
  const int tid = threadIdx.x;
  const int v = (tid < NB) ? bsum[tid] : 0;
  sd[tid] = v;
  __syncthreads();
  for (int off = 1; off < 128; off <<= 1) {
    int t = (tid >= off) ? sd[tid - off] : 0;
    __syncthreads();
    sd[tid] += t;
    __syncthreads();
  }
  if (tid < NB) bsum[tid] = sd[tid] - v;  // exclusive
}

// Local exclusive scan within each chunk + chunk base; writes offs and cur.
__global__ __launch_bounds__(256) void scanC_kernel(const int* __restrict__ cnt,
                                                    const int* __restrict__ bsum,
                                                    int* __restrict__ offs,
                                                    int* __restrict__ cur) {
  __shared__ int sd[256];
  const int base = blockIdx.x * SCAN_CHUNK;
  const int tid = threadIdx.x;
  int loc[4];
  int s = 0;
#pragma unroll
  for (int k = 0; k < 4; ++k) {
    int idx = base + tid * 4 + k;
    int c = (idx < N_NODES) ? cnt[idx] : 0;
    loc[k] = s;
    s += c;
  }
  sd[tid] = s;
  __syncthreads();
  const int mysum = s;
  for (int off = 1; off < 256; off <<= 1) {
    int t = (tid >= off) ? sd[tid - off] : 0;
    __syncthreads();
    sd[tid] += t;
    __syncthreads();
  }
  const int texcl = sd[tid] - mysum + bsum[blockIdx.x];
#pragma unroll
  for (int k = 0; k < 4; ++k) {
    int idx = base + tid * 4 + k;
    if (idx < N_NODES) {
      int o = texcl + loc[k];
      offs[idx] = o;
      cur[idx] = o;
    }
  }
}

// Scatter each edge's {src, gw} record to its CSR slot.
__global__ __launch_bounds__(256) void fill_kernel(const int* __restrict__ ei,
                                                   const float* __restrict__ attr,
                                                   const float* __restrict__ gp,
                                                   int* __restrict__ cur,
                                                   uint2* __restrict__ pairs) {
  const float inv = 1.0f / (gp[0] * gp[0] + 1e-8f);
  const int i = blockIdx.x * blockDim.x + threadIdx.x;
  const int stride = gridDim.x * blockDim.x;
  for (int e = i; e < N_EDGES; e += stride) {
    const int s = ei[e];
    const int t = ei[N_EDGES + e];
    const float d = attr[3 * e];
    const float g = __expf(-d * d * inv);
    const int pos = atomicAdd(&cur[t], 1);
    uint2 rec;
    rec.x = (unsigned)s;
    rec.y = __float_as_uint(g);
    pairs[pos] = rec;
  }
}

// One wave per node: agg[n][lane] = sum over its edges of gw * x[src][lane].
__global__ __launch_bounds__(256) void reduce_kernel(
    const float* __restrict__ x, const int* __restrict__ offs,
    const int* __restrict__ cnt, const uint2* __restrict__ pairs,
    float* __restrict__ agg) {
  const int lane = threadIdx.x & 63;
  const int w = (blockIdx.x * blockDim.x + threadIdx.x) >> 6;
  if (w >= N_NODES) return;
  const int start = offs[w];
  const int n = cnt[w];
  float acc = 0.0f;
  for (int b = 0; b < n; b += 64) {
    const int m = (n - b) < 64 ? (n - b) : 64;
    uint2 pr = {0u, 0u};
    if (lane < m) pr = pairs[start + b + lane];
    const int sj_all = (int)pr.x;
    const float gj_all = __uint_as_float(pr.y);
    for (int j = 0; j < m; ++j) {
      const int sj = __shfl(sj_all, j);
      const float gj = __shfl(gj_all, j);
      acc += gj * x[sj * CH + lane];
    }
  }
  agg[(size_t)w * CH + lane] = acc;
}

// ---------------- fallback: Round-1 atomic scatter ----------------

__global__ __launch_bounds__(256) void scatter_kernel(
    const float* __restrict__ x, const int* __restrict__ ei,
    const float* __restrict__ attr, const float* __restrict__ gp,
    float* __restrict__ agg) {
  const int lane = threadIdx.x & 63;
  const int wave = (blockIdx.x * blockDim.x + threadIdx.x) >> 6;
  const int nwaves = (gridDim.x * blockDim.x) >> 6;
  const float inv = 1.0f / (gp[0] * gp[0] + 1e-8f);
  for (int base = wave * 64; base < N_EDGES; base += nwaves * 64) {
    const int e = base + lane;
    const int s = ei[e];
    const int t = ei[N_EDGES + e];
    const float d = attr[3 * e];
    const float g = __expf(-d * d * inv);
#pragma unroll 1
    for (int j = 0; j < 64; ++j) {
      const int sj = __shfl(s, j);
      const int tj = __shfl(t, j);
      const float gj = __shfl(g, j);
      atomicAdd(&agg[(size_t)tj * CH + lane], gj * x[sj * CH + lane]);
    }
  }
}

// ---------------- stage 3: out = (x + agg) @ W + bias, in place ----------------

__global__ __launch_bounds__(256) void rowgemm_kernel(
    const float* __restrict__ x, const float* __restrict__ W,
    const float* __restrict__ bias, float* __restrict__ out) {
  const int r = blockIdx.x * blockDim.x + threadIdx.x;
  if (r >= N_NODES) return;

  const float* xr = x + (size_t)r * CH;
  float* outr = out + (size_t)r * CH;

  float s[CH];
#pragma unroll
  for (int k4 = 0; k4 < CH / 4; ++k4) {
    float4 xv = *reinterpret_cast<const float4*>(xr + k4 * 4);
    float4 av = *reinterpret_cast<const float4*>(outr + k4 * 4);
    s[k4 * 4 + 0] = xv.x + av.x;
    s[k4 * 4 + 1] = xv.y + av.y;
    s[k4 * 4 + 2] = xv.z + av.z;
    s[k4 * 4 + 3] = xv.w + av.w;
  }

  float acc[CH];
#pragma unroll
  for (int c = 0; c < CH; ++c) acc[c] = bias[c];

#pragma unroll
  for (int k = 0; k < CH; ++k) {
    const float sk = s[k];
#pragma unroll
    for (int c4 = 0; c4 < CH / 4; ++c4) {
      const float4 w = *reinterpret_cast<const float4*>(&W[k * CH + c4 * 4]);
      acc[c4 * 4 + 0] += sk * w.x;
      acc[c4 * 4 + 1] += sk * w.y;
      acc[c4 * 4 + 2] += sk * w.z;
      acc[c4 * 4 + 3] += sk * w.w;
    }
  }

#pragma unroll
  for (int c4 = 0; c4 < CH / 4; ++c4) {
    float4 o = {acc[c4 * 4 + 0], acc[c4 * 4 + 1], acc[c4 * 4 + 2],
                acc[c4 * 4 + 3]};
    *reinterpret_cast<float4*>(outr + c4 * 4) = o;
  }
}

// ---------------- launch ----------------

extern "C" void kernel_launch(void* const* d_in, const int* in_sizes, int n_in,
                              void* d_out, int out_size, void* d_ws,
                              size_t ws_size, hipStream_t stream) {
  const float* x = (const float*)d_in[0];
  const int* ei = (const int*)d_in[1];  // harness delivers int32
  const float* attr = (const float*)d_in[2];
  const float* W = (const float*)d_in[3];
  const float* bias = (const float*)d_in[4];
  const float* gp = (const float*)d_in[5];
  float* out = (float*)d_out;

  // Workspace layout (256B aligned blocks).
  const size_t sz_cnt = ((size_t)N_NODES * 4 + 255) & ~(size_t)255;
  const size_t sz_offs = sz_cnt;
  const size_t sz_cur = sz_cnt;
  const size_t sz_bsum = (128 * 4 + 255) & ~(size_t)255;
  const size_t sz_pairs = (size_t)N_EDGES * 8;
  const size_t needed = sz_cnt + sz_offs + sz_cur + sz_bsum + sz_pairs;

  if (ws_size >= needed) {
    char* base = (char*)d_ws;
    int* cnt = (int*)base;
    int* offs = (int*)(base + sz_cnt);
    int* cur = (int*)(base + sz_cnt + sz_offs);
    int* bsum = (int*)(base + sz_cnt + sz_offs + sz_cur);
    uint2* pairs = (uint2*)(base + sz_cnt + sz_offs + sz_cur + sz_bsum);

    hipMemsetAsync(cnt, 0, (size_t)N_NODES * 4, stream);
    hist_kernel<<<2048, 256, 0, stream>>>(ei, cnt);
    scanA_kernel<<<NB, 256, 0, stream>>>(cnt, bsum);
    scanB_kernel<<<1, 128, 0, stream>>>(bsum);
    scanC_kernel<<<NB, 256, 0, stream>>>(cnt, bsum, offs, cur);
    fill_kernel<<<2048, 256, 0, stream>>>(ei, attr, gp, cur, pairs);
    reduce_kernel<<<(N_NODES * 64 + 255) / 256, 256, 0, stream>>>(x, offs, cnt,
                                                                  pairs, out);
  } else {
    // Fallback: fp32 atomic scatter into d_out.
    hipMemsetAsync(out, 0, (size_t)N_NODES * CH * sizeof(float), stream);
    scatter_kernel<<<2048, 256, 0, stream>>>(x, ei, attr, gp, out);
  }

  rowgemm_kernel<<<(N_NODES + 255) / 256, 256, 0, stream>>>(x, W, bias, out);
}